// Round 1
// baseline (41052.524 us; speedup 1.0000x reference)
//
#include <hip/hip_runtime.h>
#include <math.h>
#include <stdint.h>

// Problem constants (T=1024, B=64, D=512, H=512), fp32 everywhere.
#define TT      1024
#define BATCH   64
#define HH      512
#define NG      8      // batch groups (8 rows each), keyed to blockIdx%8 (XCD locality heuristic)
#define WPG     32     // workgroups per group (H split 512/16)
#define BSL     8      // batch rows per group
#define HSL     16     // output rows per workgroup
#define NTH     512    // threads per block (8 waves)
#define SP      516    // padded LDS row stride in floats (bank-balanced, 16B aligned)
#define WLDS    (4 * 16 * SP)        // 33024 floats of weights
#define STG_FL  (8 * 256)            // 2048 floats per staging buffer (8 b-rows x 256 k)
#define LDS_FL  (WLDS + 3 * STG_FL)  // 39168 floats
#define LDS_BYTES (LDS_FL * 4)       // 156672 B  (<= 163840 B LDS/CU -> 1 block/CU)

// ---- agent-scope helpers: write-through stores / cache-bypassing loads (coherent across XCDs) ----
__device__ __forceinline__ float2 agent_ld2(const float* p) {
    unsigned long long v = __hip_atomic_load((unsigned long long*)p, __ATOMIC_RELAXED,
                                             __HIP_MEMORY_SCOPE_AGENT);
    union { unsigned long long u; float2 f; } cv; cv.u = v; return cv.f;
}
__device__ __forceinline__ void agent_st(float* p, float v) {
    __hip_atomic_store(p, v, __ATOMIC_RELAXED, __HIP_MEMORY_SCOPE_AGENT);
}

__global__ void __launch_bounds__(NTH, 2)
elman_persistent(const float* __restrict__ Xt,
                 const float* __restrict__ Wih0, const float* __restrict__ bih0,
                 const float* __restrict__ Whh0, const float* __restrict__ bhh0,
                 const float* __restrict__ Wih1, const float* __restrict__ bih1,
                 const float* __restrict__ Whh1, const float* __restrict__ bhh1,
                 float* __restrict__ out,   // [T][B][H], also serves as h1 history
                 float* h0buf,              // [2][B][H] double-buffered h0 (ws, zeroed)
                 unsigned* cnt)             // NG counters, 256B stride (ws, zeroed)
{
    extern __shared__ float lds[];
    const int tid = threadIdx.x;
    const int g   = blockIdx.x & 7;     // batch group
    const int w   = blockIdx.x >> 3;    // H-slice index
    const int jg0 = w * HSL;
    const int bg0 = g * BSL;

    float* Wl  = lds;          // [4 mats][16 rows][SP]
    float* stg = lds + WLDS;   // 3 staging buffers of 2048 floats; buf0 doubles as reduce scratch

    // ---- one-time: stage this wg's weight rows into LDS (each row: 512 floats, padded stride) ----
    for (int m = 0; m < 4; ++m) {
        const float* src = (m == 0) ? Wih0 : (m == 1) ? Whh0 : (m == 2) ? Wih1 : Whh1;
        for (int f = tid; f < 16 * 128; f += NTH) {
            int jj = f >> 7, k4 = f & 127;
            float4 v = ((const float4*)(src + (size_t)(jg0 + jj) * HH))[k4];
            *(float4*)(Wl + (m * 16 + jj) * SP + k4 * 4) = v;
        }
    }
    // bias (combined ih+hh) for the reduce/store stage threads (tid<256: layer,b,j mapping)
    float bias = 0.f;
    if (tid < 256) {
        int layer = tid >> 7, jj = tid & 15;
        bias = layer ? (bih1[jg0 + jj] + bhh1[jg0 + jj])
                     : (bih0[jg0 + jj] + bhh0[jg0 + jj]);
    }
    __syncthreads();

    // compute mapping: thread = (j in [0,16), ks in [0,32)); 8 batch accumulators per thread
    const int j      = tid & 15;
    const int ks     = tid >> 4;
    const int koff_t = ks * 8;           // this thread's k-offset within a 256-k chunk
    // staging mapping: each thread writes 16B of each chunk; wave w_i stages batch row w_i
    const int b_st = tid >> 6;
    const int k_st = (tid & 63) * 4;

    unsigned* mycnt = cnt + g * 64;      // 256B stride between group counters
    unsigned target = 0;

    float acc0[8], acc1[8];

    for (int p = 0; p <= TT; ++p) {
        const bool doL0  = (p < TT);
        const bool doL1  = (p >= 1);
        const bool hasH1 = (p >= 2);

        // ---- issue all global loads for this phase (into registers) ----
        float4 xc0 = make_float4(0.f,0.f,0.f,0.f), xc1 = xc0;
        float2 h0a0, h0a1, h0b0, h0b1;
        float2 h1a0 = {0.f,0.f}, h1a1 = h1a0, h1b0 = h1a0, h1b1 = h1a0;
        if (doL0) {
            const float* xs = Xt + ((size_t)p * BATCH + bg0 + b_st) * HH + k_st;
            xc0 = *(const float4*)(xs);
            xc1 = *(const float4*)(xs + 256);
        }
        {
            const float* hs = h0buf + (size_t)((p + 1) & 1) * (BATCH * HH)
                            + (size_t)(bg0 + b_st) * HH + k_st;
            h0a0 = agent_ld2(hs);       h0a1 = agent_ld2(hs + 2);
            h0b0 = agent_ld2(hs + 256); h0b1 = agent_ld2(hs + 258);
        }
        if (hasH1) {
            const float* hs = out + ((size_t)(p - 2) * BATCH + bg0 + b_st) * HH + k_st;
            h1a0 = agent_ld2(hs);       h1a1 = agent_ld2(hs + 2);
            h1b0 = agent_ld2(hs + 256); h1b1 = agent_ld2(hs + 258);
        }

        #pragma unroll
        for (int b = 0; b < 8; ++b) { acc0[b] = 0.f; acc1[b] = 0.f; }

        auto st4 = [&](int s, float4 v) {
            *(float4*)(stg + (s % 3) * STG_FL + b_st * 256 + k_st) = v;
        };
        // mat m weight row for this thread at chunk c: k = c*256 + koff_t + u*4
        auto compute_x = [&](int c) {   // Wih0 (mat 0) -> acc0
            const float* wr  = Wl + (0 * 16 + j) * SP + c * 256 + koff_t;
            const float* sb  = stg + (c % 3) * STG_FL;   // chunk slots 0,1 -> bufs 0,1
            #pragma unroll
            for (int u = 0; u < 2; ++u) {
                float4 wv = *(const float4*)(wr + u * 4);
                #pragma unroll
                for (int b = 0; b < 8; ++b) {
                    float4 xv = *(const float4*)(sb + b * 256 + koff_t + u * 4);
                    acc0[b] = fmaf(wv.x, xv.x, acc0[b]);
                    acc0[b] = fmaf(wv.y, xv.y, acc0[b]);
                    acc0[b] = fmaf(wv.z, xv.z, acc0[b]);
                    acc0[b] = fmaf(wv.w, xv.w, acc0[b]);
                }
            }
        };
        auto compute_h0 = [&](int c, int buf) {  // Whh0 (mat1)->acc0, Wih1 (mat2)->acc1
            const float* w0 = Wl + (1 * 16 + j) * SP + c * 256 + koff_t;
            const float* w1 = Wl + (2 * 16 + j) * SP + c * 256 + koff_t;
            const float* sb = stg + buf * STG_FL;
            #pragma unroll
            for (int u = 0; u < 2; ++u) {
                float4 wa = *(const float4*)(w0 + u * 4);
                float4 wb = *(const float4*)(w1 + u * 4);
                #pragma unroll
                for (int b = 0; b < 8; ++b) {
                    float4 xv = *(const float4*)(sb + b * 256 + koff_t + u * 4);
                    if (doL0) {
                        acc0[b] = fmaf(wa.x, xv.x, acc0[b]);
                        acc0[b] = fmaf(wa.y, xv.y, acc0[b]);
                        acc0[b] = fmaf(wa.z, xv.z, acc0[b]);
                        acc0[b] = fmaf(wa.w, xv.w, acc0[b]);
                    }
                    if (doL1) {
                        acc1[b] = fmaf(wb.x, xv.x, acc1[b]);
                        acc1[b] = fmaf(wb.y, xv.y, acc1[b]);
                        acc1[b] = fmaf(wb.z, xv.z, acc1[b]);
                        acc1[b] = fmaf(wb.w, xv.w, acc1[b]);
                    }
                }
            }
        };
        auto compute_h1 = [&](int c, int buf) {  // Whh1 (mat3) -> acc1
            const float* wr = Wl + (3 * 16 + j) * SP + c * 256 + koff_t;
            const float* sb = stg + buf * STG_FL;
            #pragma unroll
            for (int u = 0; u < 2; ++u) {
                float4 wv = *(const float4*)(wr + u * 4);
                #pragma unroll
                for (int b = 0; b < 8; ++b) {
                    float4 xv = *(const float4*)(sb + b * 256 + koff_t + u * 4);
                    acc1[b] = fmaf(wv.x, xv.x, acc1[b]);
                    acc1[b] = fmaf(wv.y, xv.y, acc1[b]);
                    acc1[b] = fmaf(wv.z, xv.z, acc1[b]);
                    acc1[b] = fmaf(wv.w, xv.w, acc1[b]);
                }
            }
        };

        // ---- 6 chunk slots through a 3-buffer LDS ring; write(s+1) overlaps compute(s) ----
        if (doL0) st4(0, xc0);                                   // buf0 <- X half 0
        __syncthreads();
        if (doL0) { st4(1, xc1); compute_x(0); }                 // buf1 <- X half 1
        __syncthreads();
        st4(2, make_float4(h0a0.x, h0a0.y, h0a1.x, h0a1.y));     // buf2 <- h0 half 0
        if (doL0) compute_x(1);
        __syncthreads();
        st4(3, make_float4(h0b0.x, h0b0.y, h0b1.x, h0b1.y));     // buf0 <- h0 half 1
        compute_h0(0, 2);
        __syncthreads();
        if (hasH1) st4(4, make_float4(h1a0.x, h1a0.y, h1a1.x, h1a1.y)); // buf1 <- h1 half 0
        compute_h0(1, 0);
        __syncthreads();
        if (hasH1) { st4(5, make_float4(h1b0.x, h1b0.y, h1b1.x, h1b1.y)); // buf2 <- h1 half 1
                     compute_h1(0, 1); }
        __syncthreads();
        if (hasH1) compute_h1(1, 2);

        // ---- reduce over ks: in-wave (4-way via shfl_xor), then cross-wave via LDS scratch ----
        #pragma unroll
        for (int b = 0; b < 8; ++b) {
            acc0[b] += __shfl_xor(acc0[b], 16);
            acc0[b] += __shfl_xor(acc0[b], 32);
            acc1[b] += __shfl_xor(acc1[b], 16);
            acc1[b] += __shfl_xor(acc1[b], 32);
        }
        const int lane = tid & 63;
        const int wv   = tid >> 6;
        // buf0 is free here (last read at compute_h0(1,0), fenced by two barriers since)
        if (lane < 16) {
            #pragma unroll
            for (int b = 0; b < 8; ++b) {
                stg[((wv * 2 + 0) * 8 + b) * 16 + lane] = acc0[b];
                stg[((wv * 2 + 1) * 8 + b) * 16 + lane] = acc1[b];
            }
        }
        __syncthreads();
        if (tid < 256) {
            const int layer = tid >> 7, b = (tid >> 4) & 7, jj = tid & 15;
            float s = 0.f;
            #pragma unroll
            for (int wq = 0; wq < 8; ++wq) s += stg[((wq * 2 + layer) * 8 + b) * 16 + jj];
            float val = tanhf(s + bias);
            if (layer == 0) {
                if (doL0) agent_st(h0buf + (size_t)(p & 1) * (BATCH * HH)
                                   + (size_t)(bg0 + b) * HH + jg0 + jj, val);
            } else {
                if (doL1) agent_st(out + ((size_t)(p - 1) * BATCH + bg0 + b) * HH + jg0 + jj, val);
            }
        }
        __threadfence();      // drain each wave's stores to the coherent point before arrival
        __syncthreads();      // (hipcc also emits vmcnt(0) before s_barrier)

        // ---- group barrier: release-add, acquire-poll ----
        if (tid == 0) {
            __hip_atomic_fetch_add(mycnt, 1u, __ATOMIC_RELEASE, __HIP_MEMORY_SCOPE_AGENT);
            target += WPG;
            while (__hip_atomic_load(mycnt, __ATOMIC_ACQUIRE, __HIP_MEMORY_SCOPE_AGENT) < target)
                __builtin_amdgcn_s_sleep(1);
        } else {
            target += WPG;
        }
        __syncthreads();
    }
}

extern "C" void kernel_launch(void* const* d_in, const int* in_sizes, int n_in,
                              void* d_out, int out_size, void* d_ws, size_t ws_size,
                              hipStream_t stream) {
    (void)in_sizes; (void)n_in; (void)out_size; (void)ws_size;
    const float* Xt   = (const float*)d_in[0];
    const float* Wih0 = (const float*)d_in[1];
    const float* bih0 = (const float*)d_in[2];
    const float* Whh0 = (const float*)d_in[3];
    const float* bhh0 = (const float*)d_in[4];
    const float* Wih1 = (const float*)d_in[5];
    const float* bih1 = (const float*)d_in[6];
    const float* Whh1 = (const float*)d_in[7];
    const float* bhh1 = (const float*)d_in[8];
    float*    out   = (float*)d_out;
    float*    h0buf = (float*)d_ws;                          // 2*64*512 floats
    unsigned* cnt   = (unsigned*)((char*)d_ws + 2 * BATCH * HH * 4);  // 8 counters, 256B stride

    // >64KB dynamic LDS opt-in (first call happens outside graph capture; idempotent after)
    hipFuncSetAttribute((const void*)elman_persistent,
                        hipFuncAttributeMaxDynamicSharedMemorySize, LDS_BYTES);
    // zero h0 double-buffer + barrier counters (ws is re-poisoned 0xAA before every launch)
    hipMemsetAsync(d_ws, 0, 2 * BATCH * HH * 4 + NG * 256, stream);

    elman_persistent<<<dim3(NG * WPG), dim3(NTH), LDS_BYTES, stream>>>(
        Xt, Wih0, bih0, Whh0, bhh0, Wih1, bih1, Whh1, bhh1, out, h0buf, cnt);
}

// Round 2
// 6986.893 us; speedup vs baseline: 5.8756x; 5.8756x over previous
//
#include <hip/hip_runtime.h>
#include <math.h>
#include <stdint.h>

// Problem constants (T=1024, B=64, D=512, H=512), fp32 everywhere.
#define TT      1024
#define BATCH   64
#define HH      512
#define NG      8      // batch groups (8 rows each)
#define WPG     32     // workgroups per group (H split 512/16)
#define BSL     8      // batch rows per group
#define HSL     16     // output rows per workgroup
#define NTH     512    // threads per block (8 waves)
#define SP      516    // padded LDS row stride in floats (16B aligned)
#define WLDS    (4 * 16 * SP)        // 33024 floats of weights
#define STG_FL  (8 * 256)            // 2048 floats per staging buffer (8 b-rows x 256 k)
#define LDS_FL  (WLDS + 3 * STG_FL)  // 39168 floats
#define LDS_BYTES (LDS_FL * 4)       // 156672 B  (<= 163840 B LDS/CU -> 1 block/CU)

// ---- LLC-coherent helpers: relaxed SYSTEM-scope atomics compile to sc0|sc1
// loads/stores (bypass L1+L2, complete at the Infinity Cache) with NO
// buffer_wbl2 / buffer_inv cache maintenance.  R1 post-mortem: acquire/release
// agent-scope ops emitted per-phase whole-L2 writeback+invalidate storms
// (40 us/phase).  Ordering is done manually with s_waitcnt vmcnt(0). ----
__device__ __forceinline__ float2 sys_ld2(const float* p) {
    unsigned long long v = __hip_atomic_load((const unsigned long long*)p, __ATOMIC_RELAXED,
                                             __HIP_MEMORY_SCOPE_SYSTEM);
    union { unsigned long long u; float2 f; } cv; cv.u = v; return cv.f;
}
__device__ __forceinline__ void sys_st(float* p, float v) {
    __hip_atomic_store(p, v, __ATOMIC_RELAXED, __HIP_MEMORY_SCOPE_SYSTEM);
}
__device__ __forceinline__ void wait_vm0() {
    asm volatile("s_waitcnt vmcnt(0)" ::: "memory");
}

__global__ void __launch_bounds__(NTH, 2)
elman_persistent(const float* __restrict__ Xt,
                 const float* __restrict__ Wih0, const float* __restrict__ bih0,
                 const float* __restrict__ Whh0, const float* __restrict__ bhh0,
                 const float* __restrict__ Wih1, const float* __restrict__ bih1,
                 const float* __restrict__ Whh1, const float* __restrict__ bhh1,
                 float* __restrict__ out,   // [T][B][H], also serves as h1 history
                 float* h0buf,              // [2][B][H] double-buffered h0 (ws, zeroed)
                 unsigned* cnt)             // NG counters, 256B stride (ws, zeroed)
{
    extern __shared__ float lds[];
    const int tid = threadIdx.x;
    const int g   = blockIdx.x & 7;     // batch group
    const int w   = blockIdx.x >> 3;    // H-slice index
    const int jg0 = w * HSL;
    const int bg0 = g * BSL;

    float* Wl  = lds;          // [4 mats][16 rows][SP]
    float* stg = lds + WLDS;   // 3 staging buffers of 2048 floats; buf0 doubles as reduce scratch

    // ---- one-time: stage this wg's weight rows into LDS ----
    for (int m = 0; m < 4; ++m) {
        const float* src = (m == 0) ? Wih0 : (m == 1) ? Whh0 : (m == 2) ? Wih1 : Whh1;
        for (int f = tid; f < 16 * 128; f += NTH) {
            int jj = f >> 7, k4 = f & 127;
            float4 v = ((const float4*)(src + (size_t)(jg0 + jj) * HH))[k4];
            *(float4*)(Wl + (m * 16 + jj) * SP + k4 * 4) = v;
        }
    }
    float bias = 0.f;
    if (tid < 256) {
        int layer = tid >> 7, jj = tid & 15;
        bias = layer ? (bih1[jg0 + jj] + bhh1[jg0 + jj])
                     : (bih0[jg0 + jj] + bhh0[jg0 + jj]);
    }
    __syncthreads();

    const int j      = tid & 15;
    const int ks     = tid >> 4;
    const int koff_t = ks * 8;
    const int b_st = tid >> 6;
    const int k_st = (tid & 63) * 4;

    unsigned* mycnt = cnt + g * 64;      // 256B stride between group counters
    unsigned target = 0;

    float acc0[8], acc1[8];

    for (int p = 0; p <= TT; ++p) {
        const bool doL0  = (p < TT);
        const bool doL1  = (p >= 1);
        const bool hasH1 = (p >= 2);

        // ---- issue all global loads for this phase ----
        float4 xc0 = make_float4(0.f,0.f,0.f,0.f), xc1 = xc0;
        float2 h0a0, h0a1, h0b0, h0b1;
        float2 h1a0 = {0.f,0.f}, h1a1 = h1a0, h1b0 = h1a0, h1b1 = h1a0;
        if (doL0) {
            const float* xs = Xt + ((size_t)p * BATCH + bg0 + b_st) * HH + k_st;
            xc0 = *(const float4*)(xs);
            xc1 = *(const float4*)(xs + 256);
        }
        {
            const float* hs = h0buf + (size_t)((p + 1) & 1) * (BATCH * HH)
                            + (size_t)(bg0 + b_st) * HH + k_st;
            h0a0 = sys_ld2(hs);       h0a1 = sys_ld2(hs + 2);
            h0b0 = sys_ld2(hs + 256); h0b1 = sys_ld2(hs + 258);
        }
        if (hasH1) {
            const float* hs = out + ((size_t)(p - 2) * BATCH + bg0 + b_st) * HH + k_st;
            h1a0 = sys_ld2(hs);       h1a1 = sys_ld2(hs + 2);
            h1b0 = sys_ld2(hs + 256); h1b1 = sys_ld2(hs + 258);
        }

        #pragma unroll
        for (int b = 0; b < 8; ++b) { acc0[b] = 0.f; acc1[b] = 0.f; }

        auto st4 = [&](int s, float4 v) {
            *(float4*)(stg + (s % 3) * STG_FL + b_st * 256 + k_st) = v;
        };
        auto compute_x = [&](int c) {   // Wih0 (mat 0) -> acc0
            const float* wr  = Wl + (0 * 16 + j) * SP + c * 256 + koff_t;
            const float* sb  = stg + (c % 3) * STG_FL;
            #pragma unroll
            for (int u = 0; u < 2; ++u) {
                float4 wv = *(const float4*)(wr + u * 4);
                #pragma unroll
                for (int b = 0; b < 8; ++b) {
                    float4 xv = *(const float4*)(sb + b * 256 + koff_t + u * 4);
                    acc0[b] = fmaf(wv.x, xv.x, acc0[b]);
                    acc0[b] = fmaf(wv.y, xv.y, acc0[b]);
                    acc0[b] = fmaf(wv.z, xv.z, acc0[b]);
                    acc0[b] = fmaf(wv.w, xv.w, acc0[b]);
                }
            }
        };
        auto compute_h0 = [&](int c, int buf) {  // Whh0 (mat1)->acc0, Wih1 (mat2)->acc1
            const float* w0 = Wl + (1 * 16 + j) * SP + c * 256 + koff_t;
            const float* w1 = Wl + (2 * 16 + j) * SP + c * 256 + koff_t;
            const float* sb = stg + buf * STG_FL;
            #pragma unroll
            for (int u = 0; u < 2; ++u) {
                float4 wa = *(const float4*)(w0 + u * 4);
                float4 wb = *(const float4*)(w1 + u * 4);
                #pragma unroll
                for (int b = 0; b < 8; ++b) {
                    float4 xv = *(const float4*)(sb + b * 256 + koff_t + u * 4);
                    if (doL0) {
                        acc0[b] = fmaf(wa.x, xv.x, acc0[b]);
                        acc0[b] = fmaf(wa.y, xv.y, acc0[b]);
                        acc0[b] = fmaf(wa.z, xv.z, acc0[b]);
                        acc0[b] = fmaf(wa.w, xv.w, acc0[b]);
                    }
                    if (doL1) {
                        acc1[b] = fmaf(wb.x, xv.x, acc1[b]);
                        acc1[b] = fmaf(wb.y, xv.y, acc1[b]);
                        acc1[b] = fmaf(wb.z, xv.z, acc1[b]);
                        acc1[b] = fmaf(wb.w, xv.w, acc1[b]);
                    }
                }
            }
        };
        auto compute_h1 = [&](int c, int buf) {  // Whh1 (mat3) -> acc1
            const float* wr = Wl + (3 * 16 + j) * SP + c * 256 + koff_t;
            const float* sb = stg + buf * STG_FL;
            #pragma unroll
            for (int u = 0; u < 2; ++u) {
                float4 wv = *(const float4*)(wr + u * 4);
                #pragma unroll
                for (int b = 0; b < 8; ++b) {
                    float4 xv = *(const float4*)(sb + b * 256 + koff_t + u * 4);
                    acc1[b] = fmaf(wv.x, xv.x, acc1[b]);
                    acc1[b] = fmaf(wv.y, xv.y, acc1[b]);
                    acc1[b] = fmaf(wv.z, xv.z, acc1[b]);
                    acc1[b] = fmaf(wv.w, xv.w, acc1[b]);
                }
            }
        };

        // ---- 6 chunk slots through a 3-buffer LDS ring ----
        if (doL0) st4(0, xc0);
        __syncthreads();
        if (doL0) { st4(1, xc1); compute_x(0); }
        __syncthreads();
        st4(2, make_float4(h0a0.x, h0a0.y, h0a1.x, h0a1.y));
        if (doL0) compute_x(1);
        __syncthreads();
        st4(3, make_float4(h0b0.x, h0b0.y, h0b1.x, h0b1.y));
        compute_h0(0, 2);
        __syncthreads();
        if (hasH1) st4(4, make_float4(h1a0.x, h1a0.y, h1a1.x, h1a1.y));
        compute_h0(1, 0);
        __syncthreads();
        if (hasH1) { st4(5, make_float4(h1b0.x, h1b0.y, h1b1.x, h1b1.y));
                     compute_h1(0, 1); }
        __syncthreads();
        if (hasH1) compute_h1(1, 2);

        // ---- reduce over ks: in-wave then cross-wave via LDS scratch ----
        #pragma unroll
        for (int b = 0; b < 8; ++b) {
            acc0[b] += __shfl_xor(acc0[b], 16);
            acc0[b] += __shfl_xor(acc0[b], 32);
            acc1[b] += __shfl_xor(acc1[b], 16);
            acc1[b] += __shfl_xor(acc1[b], 32);
        }
        const int lane = tid & 63;
        const int wv   = tid >> 6;
        if (lane < 16) {
            #pragma unroll
            for (int b = 0; b < 8; ++b) {
                stg[((wv * 2 + 0) * 8 + b) * 16 + lane] = acc0[b];
                stg[((wv * 2 + 1) * 8 + b) * 16 + lane] = acc1[b];
            }
        }
        __syncthreads();
        if (tid < 256) {
            const int layer = tid >> 7, b = (tid >> 4) & 7, jj = tid & 15;
            float s = 0.f;
            #pragma unroll
            for (int wq = 0; wq < 8; ++wq) s += stg[((wq * 2 + layer) * 8 + b) * 16 + jj];
            float val = tanhf(s + bias);
            if (layer == 0) {
                if (doL0) sys_st(h0buf + (size_t)(p & 1) * (BATCH * HH)
                                 + (size_t)(bg0 + b) * HH + jg0 + jj, val);
            } else {
                if (doL1) sys_st(out + ((size_t)(p - 1) * BATCH + bg0 + b) * HH + jg0 + jj, val);
            }
        }
        // drain this wave's LLC stores, then workgroup-converge
        wait_vm0();
        __syncthreads();

        // ---- group barrier: relaxed RMW arrival + relaxed poll (all at LLC,
        // no cache maintenance; LLC is the serialization point) ----
        if (tid == 0) {
            __hip_atomic_fetch_add(mycnt, 1u, __ATOMIC_RELAXED, __HIP_MEMORY_SCOPE_SYSTEM);
            target += WPG;
            while (__hip_atomic_load(mycnt, __ATOMIC_RELAXED, __HIP_MEMORY_SCOPE_SYSTEM) < target)
                __builtin_amdgcn_s_sleep(2);
            asm volatile("" ::: "memory");
        } else {
            target += WPG;
        }
        __syncthreads();
    }
}

extern "C" void kernel_launch(void* const* d_in, const int* in_sizes, int n_in,
                              void* d_out, int out_size, void* d_ws, size_t ws_size,
                              hipStream_t stream) {
    (void)in_sizes; (void)n_in; (void)out_size; (void)ws_size;
    const float* Xt   = (const float*)d_in[0];
    const float* Wih0 = (const float*)d_in[1];
    const float* bih0 = (const float*)d_in[2];
    const float* Whh0 = (const float*)d_in[3];
    const float* bhh0 = (const float*)d_in[4];
    const float* Wih1 = (const float*)d_in[5];
    const float* bih1 = (const float*)d_in[6];
    const float* Whh1 = (const float*)d_in[7];
    const float* bhh1 = (const float*)d_in[8];
    float*    out   = (float*)d_out;
    float*    h0buf = (float*)d_ws;                          // 2*64*512 floats
    unsigned* cnt   = (unsigned*)((char*)d_ws + 2 * BATCH * HH * 4);  // 8 counters, 256B stride

    hipFuncSetAttribute((const void*)elman_persistent,
                        hipFuncAttributeMaxDynamicSharedMemorySize, LDS_BYTES);
    hipMemsetAsync(d_ws, 0, 2 * BATCH * HH * 4 + NG * 256, stream);

    elman_persistent<<<dim3(NG * WPG), dim3(NTH), LDS_BYTES, stream>>>(
        Xt, Wih0, bih0, Whh0, bhh0, Wih1, bih1, Whh1, bhh1, out, h0buf, cnt);
}